// Round 10
// baseline (137.263 us; speedup 1.0000x reference)
//
#include <hip/hip_runtime.h>
#include <hip/hip_bf16.h>

#define T_ 4
#define B_ 4
#define C_ 256
#define H_ 32
#define W_ 32
#define TB_ 16
#define Hh_ 16
#define Wh_ 16
#define INVS2 0.70710678118654752440f
#define EPSBN 1e-5f

// Canonical weight arena offsets (bf16 elements)
#define OFF_HW   0
#define OFF_W1   4096
#define OFF_B1   4352
#define OFF_W2   4368
#define OFF_B2   6672
#define OFF_G1   6688
#define OFF_BE1  7200
#define OFF_G2   7712
#define OFF_BE2  8736
#define OFF_G3   9760
#define OFF_BE3  10016
#define OFF_G4   10272
#define OFF_BE4  10528
#define OFF_G5   10784
#define OFF_BE5  11040
#define W_TOTAL  11296
// stats arena (floats):
//   [0..1024)   unused (legacy sums1 slot, kept for layout stability)
//   [1024..3072) sums2 (BN2)        — zeroed by prep role, atomics in k_work
//   [3072..4608) sums345 (BN3/4/5)  — zeroed by prep role, atomics later
//   [4608..8704) parts1[4][4][256]  — written unconditionally by lif role
#define NSUMS    4608
#define P1OFF    4608

struct WPtrs { const void* p[15]; };

typedef __attribute__((ext_vector_type(8))) short short8;
typedef __attribute__((ext_vector_type(4))) short s16x4;
typedef __attribute__((ext_vector_type(4))) float f32x4;

__device__ inline float bf2f(__hip_bfloat16 v) { return __bfloat162float(v); }
__device__ inline float bfu(unsigned short u) { return __uint_as_float((unsigned)u << 16); }
__device__ inline unsigned short f2bfu(float v) {
    union { __hip_bfloat16 h; unsigned short u; } c;
    c.h = __float2bfloat16(v);
    return c.u;
}

// ---------------------------------------------------------------------------
// K1 k_lifprep: grid 557.
//   bids [0,512): LIF + Haar-W role, 8 pixels/thread, 2 channels/block.
//                 Per t: 2x float4 (or 1x uint4) x loads, one 8B s store,
//                 one 8B l1u store. BN1 partials to private slots (one
//                 (b,c) owner block each — no atomics, no pre-zero).
//   bids [512,557): prep role — convert weights to bf16 arena, zero
//                 sums2/sums345, block 512 publishes flag.
// ---------------------------------------------------------------------------
__global__ __launch_bounds__(256) void k_lifprep(const void* __restrict__ x_,
                                                 WPtrs wp,
                                                 __hip_bfloat16* __restrict__ wc,
                                                 float* __restrict__ stats,
                                                 int* __restrict__ flag,
                                                 unsigned char* __restrict__ s,
                                                 unsigned int* __restrict__ l1u) {
    int bid = blockIdx.x;
    int tid = threadIdx.x;

    // --- self-sniff (all blocks; identical result) ---
    const unsigned short* xr = (const unsigned short*)x_;
    int cnt = 0;
    for (int i = tid; i < 2048; i += 256) {
        int e = (xr[i] >> 7) & 0xFF;
        if (e >= 134) cnt++;
    }
    for (int o = 1; o < 64; o <<= 1) cnt += __shfl_xor(cnt, o, 64);
    __shared__ int sh[4];
    __shared__ float part[4][4];
    if ((tid & 63) == 0) sh[tid >> 6] = cnt;
    __syncthreads();
    int f = (sh[0] + sh[1] + sh[2] + sh[3] >= 32) ? 1 : 0;

    if (bid >= 512) {
        // ------------------------------ prep role ------------------------------
        int pb = bid - 512;
        if (pb == 0 && tid == 0) *flag = f;
        const int sizes[15] = {4096, 256, 16, 2304, 16, 512, 512, 1024, 1024,
                               256, 256, 256, 256, 256, 256};
        int i = pb * 256 + tid;
        if (i < W_TOTAL) {
            int seg = 0, off = 0;
            while (i >= off + sizes[seg]) { off += sizes[seg]; seg++; }
            int j = i - off;
            float v = f ? ((const float*)wp.p[seg])[j]
                        : bf2f(((const __hip_bfloat16*)wp.p[seg])[j]);
            wc[i] = __float2bfloat16(v);
        }
        if (i < 3584) stats[1024 + i] = 0.f;   // zero sums2 + sums345
        return;
    }

    // ------------------------------ LIF+Haar role ------------------------------
    int b = bid >> 7;                     // 4 batches
    int c0 = (bid & 127) * 2;             // channel pair
    int ch = tid >> 7;                    // 0/1 within pair
    int c = c0 + ch;
    int t2 = tid & 127;
    int h = t2 >> 2;                      // 32 rows
    int w8 = t2 & 3;                      // 4 octets of 8 pixels per row
    const float* xf = (const float*)x_;
    int n = ((b * 256 + c) * 32 + h) * 32 + 8 * w8;

    float v[8];
    #pragma unroll
    for (int j = 0; j < 8; ++j) v[j] = 0.f;
    float aL = 0.f, qL = 0.f, aH = 0.f, qH = 0.f;
    #pragma unroll
    for (int t = 0; t < T_; ++t) {
        size_t idx = (size_t)t * 1048576 + n;
        float x[8];
        if (f) {
            float4 xa = *(const float4*)(xf + idx);
            float4 xb = *(const float4*)(xf + idx + 4);
            x[0] = xa.x; x[1] = xa.y; x[2] = xa.z; x[3] = xa.w;
            x[4] = xb.x; x[5] = xb.y; x[6] = xb.z; x[7] = xb.w;
        } else {
            uint4 u = *(const uint4*)((const char*)x_ + idx * 2);
            x[0] = __uint_as_float(u.x << 16);
            x[1] = __uint_as_float(u.x & 0xffff0000u);
            x[2] = __uint_as_float(u.y << 16);
            x[3] = __uint_as_float(u.y & 0xffff0000u);
            x[4] = __uint_as_float(u.z << 16);
            x[5] = __uint_as_float(u.z & 0xffff0000u);
            x[6] = __uint_as_float(u.w << 16);
            x[7] = __uint_as_float(u.w & 0xffff0000u);
        }
        float sp[8];
        #pragma unroll
        for (int j = 0; j < 8; ++j) {
            v[j] += (x[j] - v[j]) * 0.5f;
            sp[j] = (v[j] >= 1.f) ? 1.f : 0.f;
            v[j] *= (1.f - sp[j]);
        }
        int tb = t * 4 + b;
        // 8B spike store
        unsigned int sA = (unsigned int)(unsigned char)sp[0]
                        | ((unsigned int)(unsigned char)sp[1] << 8)
                        | ((unsigned int)(unsigned char)sp[2] << 16)
                        | ((unsigned int)(unsigned char)sp[3] << 24);
        unsigned int sB = (unsigned int)(unsigned char)sp[4]
                        | ((unsigned int)(unsigned char)sp[5] << 8)
                        | ((unsigned int)(unsigned char)sp[6] << 16)
                        | ((unsigned int)(unsigned char)sp[7] << 24);
        *(uint2*)(s + (size_t)(tb * 256 + c) * 1024 + h * 32 + 8 * w8) =
            make_uint2(sA, sB);
        // Haar codes: units A (px 0-3) and B (px 4-7), format [cl0|cl1|ch0|ch1]
        float clA0 = sp[0] + sp[1], chA0 = sp[0] - sp[1];
        float clA1 = sp[2] + sp[3], chA1 = sp[2] - sp[3];
        float clB0 = sp[4] + sp[5], chB0 = sp[4] - sp[5];
        float clB1 = sp[6] + sp[7], chB1 = sp[6] - sp[7];
        unsigned int pkA = (unsigned int)(unsigned char)(signed char)(int)clA0
                         | ((unsigned int)(unsigned char)(signed char)(int)clA1 << 8)
                         | ((unsigned int)(unsigned char)(signed char)(int)chA0 << 16)
                         | ((unsigned int)(unsigned char)(signed char)(int)chA1 << 24);
        unsigned int pkB = (unsigned int)(unsigned char)(signed char)(int)clB0
                         | ((unsigned int)(unsigned char)(signed char)(int)clB1 << 8)
                         | ((unsigned int)(unsigned char)(signed char)(int)chB0 << 16)
                         | ((unsigned int)(unsigned char)(signed char)(int)chB1 << 24);
        l1u[(((size_t)tb * 256 + c) * 32 + h) * 8 + 2 * w8] = pkA;   // fused uint2
        l1u[(((size_t)tb * 256 + c) * 32 + h) * 8 + 2 * w8 + 1] = pkB;
        aL += clA0 + clA1 + clB0 + clB1;
        qL += clA0 * clA0 + clA1 * clA1 + clB0 * clB0 + clB1 * clB1;
        aH += chA0 + chA1 + chB0 + chB1;
        qH += chA0 * chA0 + chA1 * chA1 + chB0 * chB0 + chB1 * chB1;
    }
    for (int o = 1; o < 64; o <<= 1) {
        aL += __shfl_xor(aL, o, 64); qL += __shfl_xor(qL, o, 64);
        aH += __shfl_xor(aH, o, 64); qH += __shfl_xor(qH, o, 64);
    }
    int lane = tid & 63, wv = tid >> 6;
    if (lane == 0) {
        part[wv][0] = aL; part[wv][1] = qL; part[wv][2] = aH; part[wv][3] = qH;
    }
    __syncthreads();
    if (tid < 8) {
        int which = tid & 3;
        int cch = tid >> 2;               // 0 -> waves 0,1 (c0); 1 -> waves 2,3
        float tot = part[cch * 2][which] + part[cch * 2 + 1][which];
        // parts1[slot=b][which][c]; which: 0=aL 1=qL 2=aH 3=qH
        stats[P1OFF + (b * 4 + which) * 256 + (c0 + cch)] = tot;
    }
}

// ---------------------------------------------------------------------------
// K2 k_work: bids [0,256) = conv role (MFMA implicit GEMM -> interleaved
// cc=(y1,y2) bf162 stores + BN4/5 sums); bids [256,4352) = stage2 role
// (BN1-apply + Haar-H + gates -> l2 pixel-major q-interleaved, BN2 sums).
// l1 is uint-packed [cl0|cl1|ch0|ch1]: one 4B load/thread, all threads active.
// l2 layout: l2[(((tb*256 + c)*256 + pix)*4 + q] bf16, q = LL/HL/LH/HH.
// ---------------------------------------------------------------------------
struct SharedU {
    union {
        struct {
            short lo[1025 * 8];            // channel-last bf16, d 0..7 (+zero row)
            short hi[1025 * 8];            // d 8..15
            unsigned short w2s[2304];      // [k][d*9+tap]
            unsigned short w1s[256];       // [k][d]
            unsigned short bs[32];         // B1 | B2
            float parts[4][4][16];         // [wv][g][r*4+which]
        } cv;
        struct {
            float lo[512];
            float hi[512];
            float part[4][8];
        } s2;
    };
};

__global__ __launch_bounds__(256) void k_work(const unsigned char* __restrict__ s,
                                              const unsigned int* __restrict__ l1u,
                                              const __hip_bfloat16* __restrict__ wc,
                                              float* __restrict__ stats,
                                              __hip_bfloat16* __restrict__ l2,
                                              __hip_bfloat162* __restrict__ cc) {
    __shared__ SharedU sm;
    int bid = blockIdx.x;
    int tid = threadIdx.x;
    int lane = tid & 63, wv = tid >> 6;

    if (bid < 256) {
        // ------------------------------ conv role ------------------------------
        int img = bid;
        const unsigned short* wr = (const unsigned short*)wc;
        for (int i = tid; i < 2304; i += 256) sm.cv.w2s[i] = wr[OFF_W2 + i];
        sm.cv.w1s[tid] = wr[OFF_W1 + tid];
        if (tid < 16) { sm.cv.bs[tid] = wr[OFF_B1 + tid]; sm.cv.bs[16 + tid] = wr[OFF_B2 + tid]; }
        // zero row (pixel index 1024)
        if (tid < 8) {
            ((unsigned int*)sm.cv.lo)[4096 + (tid & 3)] = 0;
            ((unsigned int*)sm.cv.hi)[4096 + (tid & 3)] = 0;
        }
        // stage planar u8 -> LDS channel-last bf16
        {
            const unsigned int* sp = (const unsigned int*)(s + (size_t)img * 16384);
            int d2 = tid >> 5;               // channel pair 2*d2, 2*d2+1
            int pg = tid & 31;
            unsigned int* dst = (unsigned int*)((d2 < 4) ? sm.cv.lo : sm.cv.hi);
            int dl = d2 & 3;
            #pragma unroll
            for (int p = 0; p < 8; ++p) {
                int base = p * 32 + pg;      // dword index within a channel row
                unsigned int u0 = sp[d2 * 512 + base];
                unsigned int u1 = sp[d2 * 512 + 256 + base];
                #pragma unroll
                for (int jj = 0; jj < 4; ++jj) {
                    int j = (jj + pg) & 3;   // scramble to spread LDS banks
                    unsigned int b0 = (u0 >> (8 * j)) & 255u;
                    unsigned int b1 = (u1 >> (8 * j)) & 255u;
                    unsigned int val = (b0 ? 0x3F80u : 0u) | ((b1 ? 0x3F80u : 0u) << 16);
                    int pix = p * 128 + pg * 4 + j;
                    dst[pix * 4 + dl] = val;
                }
            }
        }
        __syncthreads();

        int m = lane & 15;
        int g = lane >> 4;
        const int tapA[5] = {0, 2, 4, 6, 8};
        const int tapB[5] = {1, 3, 5, 7, 8};

        short8 afr[5], a1f;
        #pragma unroll
        for (int p = 0; p < 5; ++p) {
            int tap = (g < 2) ? tapA[p] : tapB[p];
            short8 av;
            #pragma unroll
            for (int j = 0; j < 8; ++j) {
                int d = (g & 1) * 8 + j;
                unsigned short w = sm.cv.w2s[m * 144 + d * 9 + tap];
                if (p == 4 && g >= 2) w = 0;
                av[j] = (short)w;
            }
            afr[p] = av;
        }
        #pragma unroll
        for (int j = 0; j < 8; ++j) {
            int d = (g & 1) * 8 + j;
            a1f[j] = (g < 2) ? (short)sm.cv.w1s[m * 16 + d] : (short)0;
        }
        float bias1[4], bias2[4];
        #pragma unroll
        for (int r = 0; r < 4; ++r) {
            bias1[r] = bfu(sm.cv.bs[g * 4 + r]);
            bias2[r] = bfu(sm.cv.bs[16 + g * 4 + r]);
        }

        __hip_bfloat162* occ = cc + (size_t)img * 16384;
        const short* bsrc = (g & 1) ? sm.cv.hi : sm.cv.lo;

        float cs1[4] = {0, 0, 0, 0}, cq1[4] = {0, 0, 0, 0};
        float cs2[4] = {0, 0, 0, 0}, cq2[4] = {0, 0, 0, 0};

        for (int t = wv * 16; t < wv * 16 + 16; ++t) {
            int h = t >> 1;
            int w0 = (t & 1) << 4;
            f32x4 acc2 = {0.f, 0.f, 0.f, 0.f};
            f32x4 acc1 = {0.f, 0.f, 0.f, 0.f};
            #pragma unroll
            for (int p = 0; p < 5; ++p) {
                int tap = (g < 2) ? tapA[p] : tapB[p];
                int row = h + tap / 3 - 1;
                int col = w0 + m + (tap % 3) - 1;
                bool ok = ((unsigned)row < 32u) && ((unsigned)col < 32u);
                int idx = ok ? (row * 32 + col) : 1024;
                short8 bv = *(const short8*)&bsrc[idx * 8];
                acc2 = __builtin_amdgcn_mfma_f32_16x16x32_bf16(afr[p], bv, acc2, 0, 0, 0);
                if (p == 2)
                    acc1 = __builtin_amdgcn_mfma_f32_16x16x32_bf16(a1f, bv, acc1, 0, 0, 0);
            }
            int pix = h * 32 + w0 + m;
            #pragma unroll
            for (int r = 0; r < 4; ++r) {
                int k = g * 4 + r;
                float y1 = acc1[r] + bias1[r];
                float y2 = acc2[r] + bias2[r];
                __hip_bfloat162 pr;
                pr.x = __float2bfloat16(y1);
                pr.y = __float2bfloat16(y2);
                occ[(size_t)k * 1024 + pix] = pr;
                cs1[r] += y1; cq1[r] += y1 * y1;
                cs2[r] += y2; cq2[r] += y2 * y2;
            }
        }
        // reduce across the 16 m-lanes (same g)
        #pragma unroll
        for (int o = 1; o < 16; o <<= 1) {
            #pragma unroll
            for (int r = 0; r < 4; ++r) {
                cs1[r] += __shfl_xor(cs1[r], o, 64);
                cq1[r] += __shfl_xor(cq1[r], o, 64);
                cs2[r] += __shfl_xor(cs2[r], o, 64);
                cq2[r] += __shfl_xor(cq2[r], o, 64);
            }
        }
        if (m == 0) {
            #pragma unroll
            for (int r = 0; r < 4; ++r) {
                sm.cv.parts[wv][g][r * 4 + 0] = cs1[r];
                sm.cv.parts[wv][g][r * 4 + 1] = cq1[r];
                sm.cv.parts[wv][g][r * 4 + 2] = cs2[r];
                sm.cv.parts[wv][g][r * 4 + 3] = cq2[r];
            }
        }
        __syncthreads();
        if (tid < 64) {
            int gg = tid >> 4, r = (tid >> 2) & 3, which = tid & 3;
            float tot = sm.cv.parts[0][gg][r * 4 + which] + sm.cv.parts[1][gg][r * 4 + which]
                      + sm.cv.parts[2][gg][r * 4 + which] + sm.cv.parts[3][gg][r * 4 + which];
            int ch = (img & 15) * 16 + gg * 4 + r;   // global BN channel
            // stats: sums4_sum@3584 sums4_sq@3840 sums5_sum@4096 sums5_sq@4352
            const int base[4] = {3584, 3840, 4096, 4352};
            atomicAdd(&stats[base[which] + ch], tot);
        }
    } else {
        // ------------------------------ stage2 role ------------------------------
        int blk = bid - 256;                  // TB*C = 4096
        int c = blk & 255;
        int tb = blk >> 8;

        // BN1 raw sums: sum the 4 parts1 slots
        const float* p1 = stats + P1OFF;
        float aLs = 0.f, qLs = 0.f, aHs = 0.f, qHs = 0.f;
        #pragma unroll
        for (int slot = 0; slot < 4; ++slot) {
            aLs += p1[(slot * 4 + 0) * 256 + c];
            qLs += p1[(slot * 4 + 1) * 256 + c];
            aHs += p1[(slot * 4 + 2) * 256 + c];
            qHs += p1[(slot * 4 + 3) * 256 + c];
        }

        const float nrm = 1.f / 8192.f;
        float mL = aLs * INVS2 * nrm;
        float vL = fmaxf(qLs * 0.5f * nrm - mL * mL, 0.f);
        float sL = bf2f(wc[OFF_G1 + c]) * rsqrtf(vL + EPSBN);
        float tL = bf2f(wc[OFF_BE1 + c]) - mL * sL;
        float mH = aHs * INVS2 * nrm;
        float vH = fmaxf(qHs * 0.5f * nrm - mH * mH, 0.f);
        float sH = bf2f(wc[OFF_G1 + 256 + c]) * rsqrtf(vH + EPSBN);
        float tH = bf2f(wc[OFF_BE1 + 256 + c]) - mH * sH;

        float slo = sL * INVS2, shi = sH * INVS2;
        // one packed 4B load per thread: [cl0|cl1|ch0|ch1]
        {
            unsigned int v = l1u[((size_t)tb * 256 + c) * 256 + tid];
            int h = tid >> 3, wq = tid & 7;
            float lo0 = (float)(signed char)(v & 0xFF) * slo + tL;
            float lo1 = (float)(signed char)((v >> 8) & 0xFF) * slo + tL;
            float hi0 = (float)(signed char)((v >> 16) & 0xFF) * shi + tH;
            float hi1 = (float)(signed char)(v >> 24) * shi + tH;
            *(float2*)&sm.s2.lo[h * 16 + 2 * wq] = make_float2(lo0, lo1);
            *(float2*)&sm.s2.hi[h * 16 + 2 * wq] = make_float2(hi0, hi1);
        }
        __syncthreads();

        int w = tid & 15, v = tid >> 4;
        float a = sm.s2.lo[(2 * v) * Wh_ + w], b = sm.s2.lo[(2 * v + 1) * Wh_ + w];
        float zLL = (a + b) * INVS2;
        float zHL = (a - b) * INVS2;
        a = sm.s2.hi[(2 * v) * Wh_ + w]; b = sm.s2.hi[(2 * v + 1) * Wh_ + w];
        float zLH = (a + b) * INVS2;
        float zHH = (a - b) * INVS2;
        zLL = (fabsf(zLL) - 0.5f >= 0.f) ? zLL : 0.f;
        zHL = (fabsf(zHL) - 0.5f >= 0.f) ? zHL : 0.f;
        zLH = (fabsf(zLH) - 0.5f >= 0.f) ? zLH : 0.f;
        zHH = (fabsf(zHH) - 0.5f >= 0.f) ? zHH : 0.f;

        float r0 = zLL, r1 = zHL, r2 = zLH, r3 = zHH;
        float q0 = zLL * zLL, q1 = zHL * zHL, q2 = zLH * zLH, q3 = zHH * zHH;
        for (int o = 1; o < 64; o <<= 1) {
            r0 += __shfl_xor(r0, o, 64); r1 += __shfl_xor(r1, o, 64);
            r2 += __shfl_xor(r2, o, 64); r3 += __shfl_xor(r3, o, 64);
            q0 += __shfl_xor(q0, o, 64); q1 += __shfl_xor(q1, o, 64);
            q2 += __shfl_xor(q2, o, 64); q3 += __shfl_xor(q3, o, 64);
        }
        if (lane == 0) {
            sm.s2.part[wv][0] = r0; sm.s2.part[wv][1] = r1;
            sm.s2.part[wv][2] = r2; sm.s2.part[wv][3] = r3;
            sm.s2.part[wv][4] = q0; sm.s2.part[wv][5] = q1;
            sm.s2.part[wv][6] = q2; sm.s2.part[wv][7] = q3;
        }
        __syncthreads();
        float S0 = sm.s2.part[0][0] + sm.s2.part[1][0] + sm.s2.part[2][0] + sm.s2.part[3][0];
        float S1 = sm.s2.part[0][1] + sm.s2.part[1][1] + sm.s2.part[2][1] + sm.s2.part[3][1];
        float S2 = sm.s2.part[0][2] + sm.s2.part[1][2] + sm.s2.part[2][2] + sm.s2.part[3][2];
        float S3 = sm.s2.part[0][3] + sm.s2.part[1][3] + sm.s2.part[2][3] + sm.s2.part[3][3];
        float Q0 = sm.s2.part[0][4] + sm.s2.part[1][4] + sm.s2.part[2][4] + sm.s2.part[3][4];
        float Q1 = sm.s2.part[0][5] + sm.s2.part[1][5] + sm.s2.part[2][5] + sm.s2.part[3][5];
        float Q2 = sm.s2.part[0][6] + sm.s2.part[1][6] + sm.s2.part[2][6] + sm.s2.part[3][6];
        float Q3 = sm.s2.part[0][7] + sm.s2.part[1][7] + sm.s2.part[2][7] + sm.s2.part[3][7];
        float fLL = (Q0 * (1.f / 256.f) > 0.01f) ? 1.f : 0.f;
        float fHL = (Q1 * (1.f / 256.f) > 0.02f) ? 1.f : 0.f;
        float fLH = (Q2 * (1.f / 256.f) > 0.02f) ? 1.f : 0.f;
        float fHH = (Q3 * (1.f / 256.f) > 0.05f) ? 1.f : 0.f;

        float* sums2 = stats + 1024;
        if (tid < 8) {
            const int cho[8] = {0, 1024, 256, 1280, 512, 1536, 768, 1792};
            const float vals[8] = {fLL * S0, fLL * Q0, fHL * S1, fHL * Q1,
                                   fLH * S2, fLH * Q2, fHH * S3, fHH * Q3};
            atomicAdd(&sums2[cho[tid] + c], vals[tid]);
        }

        // pixel-major q-interleaved store: one 8B store per thread
        size_t ob = (((size_t)tb * 256) + c) * 256 + tid;
        s16x4 pk;
        pk[0] = (short)f2bfu(zLL * fLL);
        pk[1] = (short)f2bfu(zHL * fHL);
        pk[2] = (short)f2bfu(zLH * fLH);
        pk[3] = (short)f2bfu(zHH * fHH);
        *(s16x4*)(l2 + 4 * ob) = pk;
    }
}

// ---------------------------------------------------------------------------
// K3 k_mixinv: BN2-apply + block channel matmul + inverse Haar -> rec bf16;
// accumulates BN3 raw sums. Grid 1024 = tb(16) x cg(16) x ks(4): each block
// computes 4 of the 16 output channels (4 blocks/CU). l2 is pixel-major
// q-interleaved: one 8B load yields all four q-planes for (d, pixel).
// ---------------------------------------------------------------------------
__global__ __launch_bounds__(256) void k_mixinv(const __hip_bfloat16* __restrict__ l2,
                                                const __hip_bfloat16* __restrict__ wc,
                                                float* __restrict__ stats,
                                                __hip_bfloat16* __restrict__ rec) {
    int bid = blockIdx.x;                 // 1024 = tb(16) * cg(16) * ks(4)
    int ks = bid & 3;
    int cg = (bid >> 2) & 15;
    int tb = bid >> 6;
    int tid = threadIdx.x;
    int lane = tid & 63, wvv = tid >> 6;
    const float* sums2 = stats + 1024;

    __shared__ float wt[4][16][4];        // [q][d][kk] for k = ks*4+kk
    __shared__ float bsc[64], bsh[64];
    __shared__ float parts2[4][8];
    {
        int i = tid;                      // 256 entries = q(4) * d(16) * kk(4)
        int q = i >> 6, rem = i & 63, d = rem >> 2, kk = rem & 3;
        int nb = q * 4 + (cg >> 2);
        int k = ks * 4 + kk;
        wt[q][d][kk] = bf2f(wc[OFF_HW + nb * 256 + d * 16 + k]);
    }
    if (tid < 64) {
        int q = tid >> 4, d = tid & 15;
        int ch = q * 256 + cg * 16 + d;
        float m = sums2[ch] * (1.f / 4096.f);
        float var = fmaxf(sums2[1024 + ch] * (1.f / 4096.f) - m * m, 0.f);
        float sc = bf2f(wc[OFF_G2 + ch]) * rsqrtf(var + EPSBN);
        bsc[tid] = sc;
        bsh[tid] = bf2f(wc[OFF_BE2 + ch]) - m * sc;
    }
    __syncthreads();

    float h[4][4];
    #pragma unroll
    for (int q = 0; q < 4; ++q)
        #pragma unroll
        for (int kk = 0; kk < 4; ++kk) h[q][kk] = 0.f;

    int p = tid;
    #pragma unroll
    for (int d = 0; d < 16; ++d) {
        s16x4 pk = *(const s16x4*)(l2 + 4 * (((size_t)tb * 256 + cg * 16 + d) * 256 + p));
        #pragma unroll
        for (int q = 0; q < 4; ++q) {
            float xv = bfu((unsigned short)pk[q]) * bsc[q * 16 + d] + bsh[q * 16 + d];
            #pragma unroll
            for (int kk = 0; kk < 4; ++kk)
                h[q][kk] = fmaf(xv, wt[q][d][kk], h[q][kk]);
        }
    }

    int uh = tid >> 4, uw = tid & 15;
    __hip_bfloat16* ob = rec + ((size_t)tb * 256 + cg * 16) * 1024;
    float sk[4], qk[4];
    #pragma unroll
    for (int kk = 0; kk < 4; ++kk) {
        int k = ks * 4 + kk;
        float LL = h[0][kk], HL = h[1][kk], LH = h[2][kk], HH = h[3][kk];
        float v00 = 0.5f * (LL + HL + LH + HH);
        float v01 = 0.5f * (LL + HL - LH - HH);
        float v10 = 0.5f * (LL - HL + LH - HH);
        float v11 = 0.5f * (LL - HL - LH + HH);
        __hip_bfloat162 top, bot;
        top.x = __float2bfloat16(v00); top.y = __float2bfloat16(v01);
        bot.x = __float2bfloat16(v10); bot.y = __float2bfloat16(v11);
        *(__hip_bfloat162*)(ob + (size_t)k * 1024 + (2 * uh) * 32 + 2 * uw) = top;
        *(__hip_bfloat162*)(ob + (size_t)k * 1024 + (2 * uh + 1) * 32 + 2 * uw) = bot;
        sk[kk] = v00 + v01 + v10 + v11;
        qk[kk] = v00 * v00 + v01 * v01 + v10 * v10 + v11 * v11;
    }
    for (int o = 1; o < 64; o <<= 1) {
        #pragma unroll
        for (int kk = 0; kk < 4; ++kk) {
            sk[kk] += __shfl_xor(sk[kk], o, 64);
            qk[kk] += __shfl_xor(qk[kk], o, 64);
        }
    }
    if (lane == 0) {
        #pragma unroll
        for (int kk = 0; kk < 4; ++kk) {
            parts2[wvv][kk * 2]     = sk[kk];
            parts2[wvv][kk * 2 + 1] = qk[kk];
        }
    }
    __syncthreads();
    if (tid < 8) {
        int kk = tid >> 1, which = tid & 1;
        float tot = parts2[0][tid] + parts2[1][tid] + parts2[2][tid] + parts2[3][tid];
        atomicAdd(&stats[3072 + which * 256 + cg * 16 + ks * 4 + kk], tot);
    }
}

// ---------------------------------------------------------------------------
// K4 k_final: elementwise combine, 8 elems/thread (grid 2048); derives
// BN3/4/5 coefficients from raw sums (8-elem groups never cross a channel
// row). 16B vectorized loads/stores.
// ---------------------------------------------------------------------------
__global__ __launch_bounds__(256) void k_final(const __hip_bfloat16* __restrict__ rec,
                                               const __hip_bfloat162* __restrict__ cc,
                                               const float* __restrict__ stats,
                                               const __hip_bfloat16* __restrict__ wc,
                                               const int* __restrict__ flag,
                                               void* __restrict__ out_) {
    int n8 = blockIdx.x * 256 + threadIdx.x;    // 8-elem group index
    int c = ((n8 * 8) >> 10) & 255;             // uniform within group
    const float inv = 1.f / 16384.f;
    float m3 = stats[3072 + c] * inv;
    float v3 = fmaxf(stats[3328 + c] * inv - m3 * m3, 0.f);
    float sc3 = bf2f(wc[OFF_G3 + c]) * rsqrtf(v3 + EPSBN);
    float sh3 = bf2f(wc[OFF_BE3 + c]) - m3 * sc3;
    float m4 = stats[3584 + c] * inv;
    float v4 = fmaxf(stats[3840 + c] * inv - m4 * m4, 0.f);
    float sc4 = bf2f(wc[OFF_G4 + c]) * rsqrtf(v4 + EPSBN);
    float sh4 = bf2f(wc[OFF_BE4 + c]) - m4 * sc4;
    float m5 = stats[4096 + c] * inv;
    float v5 = fmaxf(stats[4352 + c] * inv - m5 * m5, 0.f);
    float sc5 = bf2f(wc[OFF_G5 + c]) * rsqrtf(v5 + EPSBN);
    float sh5 = bf2f(wc[OFF_BE5 + c]) - m5 * sc5;
    float shS = sh3 + sh4 + sh5;

    short8 r8 = ((const short8*)rec)[n8];          // 8 bf16 rec values (16B)
    short8 pA = ((const short8*)cc)[2 * n8];       // pairs for elems 0..3
    short8 pB = ((const short8*)cc)[2 * n8 + 1];   // pairs for elems 4..7

    float o[8];
    #pragma unroll
    for (int j = 0; j < 4; ++j) {
        o[j]     = bfu((unsigned short)r8[j]) * sc3
                 + bfu((unsigned short)pA[2 * j]) * sc4
                 + bfu((unsigned short)pA[2 * j + 1]) * sc5 + shS;
        o[4 + j] = bfu((unsigned short)r8[4 + j]) * sc3
                 + bfu((unsigned short)pB[2 * j]) * sc4
                 + bfu((unsigned short)pB[2 * j + 1]) * sc5 + shS;
    }

    if (*flag) {
        ((float4*)out_)[2 * n8]     = make_float4(o[0], o[1], o[2], o[3]);
        ((float4*)out_)[2 * n8 + 1] = make_float4(o[4], o[5], o[6], o[7]);
    } else {
        short8 ov;
        #pragma unroll
        for (int j = 0; j < 8; ++j) ov[j] = (short)f2bfu(o[j]);
        ((short8*)out_)[n8] = ov;
    }
}

// ---------------------------------------------------------------------------
// Workspace map:
//   [0,4M):   s (planar u8 spikes)      [4,8M):  l1u (packed uint codes)
//   [8,16M):  l2 (pixel-major q-interleaved bf16)
//   [16,24M): rec                       [24,40M): cc (y1,y2 bf162 pairs)
//   [40M..):  weight arena, stats(8704 fl incl parts1), flag
// ---------------------------------------------------------------------------
extern "C" void kernel_launch(void* const* d_in, const int* in_sizes, int n_in,
                              void* d_out, int out_size, void* d_ws, size_t ws_size,
                              hipStream_t stream) {
    char* ws = (char*)d_ws;
    unsigned char* s_u8  = (unsigned char*)ws;
    unsigned int* l1u    = (unsigned int*)(ws + ((size_t)4 << 20));
    __hip_bfloat16* l2   = (__hip_bfloat16*)(ws + ((size_t)8 << 20));
    __hip_bfloat16* rec  = (__hip_bfloat16*)(ws + ((size_t)16 << 20));
    __hip_bfloat162* cc  = (__hip_bfloat162*)(ws + ((size_t)24 << 20));
    __hip_bfloat16* wc   = (__hip_bfloat16*)(ws + ((size_t)40 << 20));
    float* stats         = (float*)(ws + ((size_t)40 << 20) + (64 << 10));
    int* flag            = (int*)(ws + ((size_t)40 << 20) + (128 << 10));

    WPtrs wp;
    for (int i = 0; i < 15; ++i) wp.p[i] = d_in[i + 1];

    dim3 blk(256);
    k_lifprep<<<dim3(557), blk, 0, stream>>>(d_in[0], wp, wc, stats, flag, s_u8, l1u);
    k_work<<<dim3(4352), blk, 0, stream>>>(s_u8, l1u, wc, stats, l2, cc);
    k_mixinv<<<dim3(1024), blk, 0, stream>>>(l2, wc, stats, rec);
    k_final<<<dim3(2048), blk, 0, stream>>>(rec, cc, stats, wc, flag, d_out);
}